// Round 17
// baseline (96.898 us; speedup 1.0000x reference)
//
#include <hip/hip_runtime.h>
#include <math.h>

#define N_ROWS 65536
#define M_DIM  512
#define H_DIM  1024
#define EPS    1e-8f
#define NBLK_S 1024   // k_simexp blocks (64 rows each, 16 per wave)
#define NBLK_U 2048   // k_update stream blocks (32 rows each); +64 merge blocks

typedef float f32x4 __attribute__((ext_vector_type(4)));
typedef unsigned int u32;

__device__ __forceinline__ float sigmoidf_(float v) { return 1.f / (1.f + expf(-v)); }

// ---- workspace layout (floats) ----
#define WS_KVEC  0          // 512
#define WS_ERASE 512        // 512
#define WS_ADD   1024       // 512
#define WS_SCAL  1536       // [0]=beta_raw
#define WS_CTR   1552       // 8 u32 election counters
#define WS_P     2048       // 65536 unnormalized exp(beta*sim)
#define WS_PSUM  67584      // 1024 per-simexp-block Σp
#define WS_P2SUM 68608      // 1024 per-simexp-block Σp²
#define WS_PART1 69632      // 1024*512 per-block Σ p·mem
#define WS_PART2 593920     // 1024*512 per-block Σ p²·mem
#define WS_O1A   1118208    // 64*512
#define WS_O1B   1150976    // 64*512

// ---- fused gates matvec + LSTM cell: 1024 blocks x 256; block 0 zeroes counters ----
__global__ void __launch_bounds__(256) k_gatecell(
        const float* __restrict__ x, const float* __restrict__ rv,
        const float* __restrict__ h0, const float* __restrict__ c0,
        const float* __restrict__ W_ih, const float* __restrict__ b_ih,
        const float* __restrict__ W_hh, const float* __restrict__ b_hh,
        float* __restrict__ h_out, float* __restrict__ c_out,
        u32* __restrict__ ctr) {
    __shared__ float gval[4];
    if (blockIdx.x == 0 && threadIdx.x < 8) ctr[threadIdx.x] = 0u;
    int j = blockIdx.x;
    int wid = threadIdx.x >> 6;
    int lane = threadIdx.x & 63;
    int r = wid * H_DIM + j;
    const float4* Wi = (const float4*)(W_ih + (size_t)r * 1024);
    const float4* Wh = (const float4*)(W_hh + (size_t)r * 1024);
    const float4* xv = (const float4*)x;
    const float4* rvv = (const float4*)rv;
    const float4* hv = (const float4*)h0;
    float s = 0.f;
#pragma unroll
    for (int k = 0; k < 4; ++k) {
        int idx = k * 64 + lane;
        float4 wiv = Wi[idx];
        float4 in4 = (k < 2) ? xv[idx] : rvv[idx - 128];
        s += wiv.x * in4.x + wiv.y * in4.y + wiv.z * in4.z + wiv.w * in4.w;
        float4 whv = Wh[idx];
        float4 h4 = hv[idx];
        s += whv.x * h4.x + whv.y * h4.y + whv.z * h4.z + whv.w * h4.w;
    }
#pragma unroll
    for (int o = 32; o > 0; o >>= 1) s += __shfl_xor(s, o);
    if (lane == 0) gval[wid] = s + b_ih[r] + b_hh[r];
    __syncthreads();
    if (threadIdx.x == 0) {
        float ig = sigmoidf_(gval[0]);
        float fg = sigmoidf_(gval[1]);
        float gg = tanhf(gval[2]);
        float og = sigmoidf_(gval[3]);
        float c = fg * c0[j] + ig * gg;
        float h = og * tanhf(c);
        c_out[j] = c;
        h_out[j] = h;
    }
}

// ---- 5 head matvecs vs h; one wave per output row ----
__global__ void __launch_bounds__(256) k_heads(
        const float* __restrict__ h,
        const float* __restrict__ W_fc, const float* __restrict__ b_fc,
        const float* __restrict__ W_key, const float* __restrict__ b_key,
        const float* __restrict__ W_beta, const float* __restrict__ b_beta,
        const float* __restrict__ W_erase, const float* __restrict__ b_erase,
        const float* __restrict__ W_add, const float* __restrict__ b_add,
        float* __restrict__ out, float* __restrict__ kvec,
        float* __restrict__ scal, float* __restrict__ erase,
        float* __restrict__ addv) {
    int wave = (blockIdx.x * blockDim.x + threadIdx.x) >> 6;
    int lane = threadIdx.x & 63;
    if (wave >= 2049) return;
    const float* Wrow;
    float bias;
    int kind, r;
    if (wave < 512)        { kind = 0; r = wave;        Wrow = W_fc    + (size_t)r * 1024; bias = b_fc[r]; }
    else if (wave < 1024)  { kind = 1; r = wave - 512;  Wrow = W_key   + (size_t)r * 1024; bias = b_key[r]; }
    else if (wave == 1024) { kind = 2; r = 0;           Wrow = W_beta;                     bias = b_beta[0]; }
    else if (wave < 1537)  { kind = 3; r = wave - 1025; Wrow = W_erase + (size_t)r * 1024; bias = b_erase[r]; }
    else                   { kind = 4; r = wave - 1537; Wrow = W_add   + (size_t)r * 1024; bias = b_add[r]; }
    const float4* Wv = (const float4*)Wrow;
    const float4* hv = (const float4*)h;
    float s = 0.f;
#pragma unroll
    for (int k = 0; k < 4; ++k) {
        int idx = k * 64 + lane;
        float4 w4 = Wv[idx];
        float4 h4 = hv[idx];
        s += w4.x * h4.x + w4.y * h4.y + w4.z * h4.z + w4.w * h4.w;
    }
#pragma unroll
    for (int o = 32; o > 0; o >>= 1) s += __shfl_xor(s, o);
    if (lane == 0) {
        float v = s + bias;
        if (kind == 0)      out[r]   = sigmoidf_(v);
        else if (kind == 1) kvec[r]  = tanhf(v);
        else if (kind == 2) scal[0]  = v;
        else if (kind == 3) erase[r] = sigmoidf_(v);
        else                addv[r]  = tanhf(v);
    }
}

// ---- pass A: p[n]=exp(beta*cos); accumulate per-block R1=Σp·mem, R2=Σp²·mem ----
__global__ void __launch_bounds__(256) k_simexp(
        const float* __restrict__ mem, const float* __restrict__ kvec,
        const float* __restrict__ scal,
        float* __restrict__ p, float* __restrict__ psum, float* __restrict__ p2sum,
        float* __restrict__ part1, float* __restrict__ part2) {
    __shared__ float red[256];
    __shared__ float skn[512];
    __shared__ float wsum[4];
    __shared__ float w2sum[4];
    __shared__ float4 s1[4][128];
    __shared__ float4 s2[4][128];
    int t = threadIdx.x;
    float v0 = kvec[t];
    float v1 = kvec[t + 256];
    red[t] = v0 * v0 + v1 * v1;
    __syncthreads();
#pragma unroll
    for (int s2_ = 128; s2_ > 0; s2_ >>= 1) {
        if (t < s2_) red[t] += red[t + s2_];
        __syncthreads();
    }
    float invn = 1.f / (sqrtf(red[0]) + EPS);
    float braw = scal[0];
    float beta = ((braw > 20.f) ? braw : log1pf(expf(braw))) + EPS;
    skn[t] = v0 * invn;
    skn[t + 256] = v1 * invn;
    __syncthreads();
    int wid = t >> 6, lane = t & 63;
    float4 k0 = ((const float4*)skn)[lane];
    float4 k1 = ((const float4*)skn)[64 + lane];
    size_t base = ((size_t)blockIdx.x * 4 + wid) * 16;   // 16 rows per wave
    float lsum = 0.f, l2sum = 0.f;
    float4 a1lo = make_float4(0.f,0.f,0.f,0.f), a1hi = make_float4(0.f,0.f,0.f,0.f);
    float4 a2lo = make_float4(0.f,0.f,0.f,0.f), a2hi = make_float4(0.f,0.f,0.f,0.f);
#pragma unroll 2
    for (int i = 0; i < 16; ++i) {
        size_t row = base + i;
        const float4* mv = (const float4*)(mem + row * M_DIM);
        float4 m0 = mv[lane];
        float4 m1 = mv[64 + lane];
        float dot = m0.x * k0.x + m0.y * k0.y + m0.z * k0.z + m0.w * k0.w
                  + m1.x * k1.x + m1.y * k1.y + m1.z * k1.z + m1.w * k1.w;
        float ss  = m0.x * m0.x + m0.y * m0.y + m0.z * m0.z + m0.w * m0.w
                  + m1.x * m1.x + m1.y * m1.y + m1.z * m1.z + m1.w * m1.w;
#pragma unroll
        for (int o = 32; o > 0; o >>= 1) {
            dot += __shfl_xor(dot, o);
            ss  += __shfl_xor(ss, o);
        }
        float pe = expf(beta * (dot / (sqrtf(ss) + EPS)));
        if (lane == 0) p[row] = pe;
        float pe2 = pe * pe;
        lsum += pe;
        l2sum += pe2;
        a1lo.x += pe * m0.x;  a1lo.y += pe * m0.y;  a1lo.z += pe * m0.z;  a1lo.w += pe * m0.w;
        a1hi.x += pe * m1.x;  a1hi.y += pe * m1.y;  a1hi.z += pe * m1.z;  a1hi.w += pe * m1.w;
        a2lo.x += pe2 * m0.x; a2lo.y += pe2 * m0.y; a2lo.z += pe2 * m0.z; a2lo.w += pe2 * m0.w;
        a2hi.x += pe2 * m1.x; a2hi.y += pe2 * m1.y; a2hi.z += pe2 * m1.z; a2hi.w += pe2 * m1.w;
    }
    s1[wid][lane] = a1lo;  s1[wid][64 + lane] = a1hi;
    s2[wid][lane] = a2lo;  s2[wid][64 + lane] = a2hi;
    if (lane == 0) { wsum[wid] = lsum; w2sum[wid] = l2sum; }
    __syncthreads();
    if (t < 128) {
        float4 A = s1[0][t], B = s1[1][t], C = s1[2][t], D = s1[3][t];
        float4 r4;
        r4.x = (A.x + B.x) + (C.x + D.x);
        r4.y = (A.y + B.y) + (C.y + D.y);
        r4.z = (A.z + B.z) + (C.z + D.z);
        r4.w = (A.w + B.w) + (C.w + D.w);
        ((float4*)(part1 + (size_t)blockIdx.x * M_DIM))[t] = r4;
    } else {
        int u = t - 128;
        float4 A = s2[0][u], B = s2[1][u], C = s2[2][u], D = s2[3][u];
        float4 r4;
        r4.x = (A.x + B.x) + (C.x + D.x);
        r4.y = (A.y + B.y) + (C.y + D.y);
        r4.z = (A.z + B.z) + (C.z + D.z);
        r4.w = (A.w + B.w) + (C.w + D.w);
        ((float4*)(part2 + (size_t)blockIdx.x * M_DIM))[u] = r4;
    }
    if (t == 0) {
        psum[blockIdx.x]  = (wsum[0] + wsum[1]) + (wsum[2] + wsum[3]);
        p2sum[blockIdx.x] = (w2sum[0] + w2sum[1]) + (w2sum[2] + w2sum[3]);
    }
}

// ---- pass B: 2112 blocks. 0..2047 stream mem_new (reverse row order for L3 recency);
//      2048..2111 merge stage 1; elected last merge block computes read_out ----
__global__ void __launch_bounds__(256) k_update(
        const float* __restrict__ mem, const float* __restrict__ p,
        const float* __restrict__ psum, const float* __restrict__ p2sum,
        const float* __restrict__ part1, const float* __restrict__ part2,
        const float* __restrict__ erase, const float* __restrict__ addv,
        float* __restrict__ mem_out, float* __restrict__ read_out,
        float* __restrict__ o1a, float* __restrict__ o1b,
        u32* __restrict__ ctr) {
    int t = threadIdx.x;

    if (blockIdx.x >= NBLK_U) {
        // ---- merge stage 1: 64 blocks; block g sums partials g*16..g*16+15 ----
        int g = blockIdx.x - NBLK_U;
        float s0 = 0.f, s1 = 0.f, s2 = 0.f, s3 = 0.f;
        int b0 = g * 16;
#pragma unroll 4
        for (int b = b0; b < b0 + 16; ++b) {
            s0 += part1[(size_t)b * M_DIM + t];
            s1 += part1[(size_t)b * M_DIM + 256 + t];
            s2 += part2[(size_t)b * M_DIM + t];
            s3 += part2[(size_t)b * M_DIM + 256 + t];
        }
        o1a[(size_t)g * M_DIM + t] = s0;
        o1a[(size_t)g * M_DIM + 256 + t] = s1;
        o1b[(size_t)g * M_DIM + t] = s2;
        o1b[(size_t)g * M_DIM + 256 + t] = s3;
        // ---- election among 64 merge blocks (small dirty footprint ~8KB each) ----
        __shared__ bool isLast;
        __threadfence();
        __syncthreads();
        if (t == 0) isLast = (atomicAdd(&ctr[0], 1u) == 63u);
        __syncthreads();
        if (isLast) {
            __threadfence();   // acquire: make other blocks' o1a/o1b visible
            __shared__ float red[256];
            __shared__ float red2[256];
            float s = 0.f, s2v = 0.f;
#pragma unroll
            for (int i = 0; i < 4; ++i) {
                s   += psum[t + i * 256];
                s2v += p2sum[t + i * 256];
            }
            red[t] = s;
            red2[t] = s2v;
            __syncthreads();
#pragma unroll
            for (int s2_ = 128; s2_ > 0; s2_ >>= 1) {
                if (t < s2_) { red[t] += red[t + s2_]; red2[t] += red2[t + s2_]; }
                __syncthreads();
            }
            float invS  = 1.f / red[0];
            float sumP2 = red2[0];
            float invSS = invS * invS;
#pragma unroll
            for (int m = t; m < M_DIM; m += 256) {
                float r1 = 0.f, r2 = 0.f;
#pragma unroll 8
                for (int gg = 0; gg < 64; ++gg) {
                    r1 += o1a[(size_t)gg * M_DIM + m];
                    r2 += o1b[(size_t)gg * M_DIM + m];
                }
                read_out[m] = r1 * invS - erase[m] * r2 * invSS + addv[m] * sumP2 * invSS;
            }
        }
        return;
    }

    // ---- stream blocks ----
    __shared__ float red[256];
    __shared__ float4 s_e[128];
    __shared__ float4 s_a[128];
    __shared__ float  s_w[32];
    float s = 0.f;
#pragma unroll
    for (int i = 0; i < 4; ++i) s += psum[t + i * 256];
    red[t] = s;
    __syncthreads();
#pragma unroll
    for (int s2_ = 128; s2_ > 0; s2_ >>= 1) {
        if (t < s2_) red[t] += red[t + s2_];
        __syncthreads();
    }
    float winv = 1.f / red[0];
    if (t < 128) {
        s_e[t] = ((const float4*)erase)[t];
        s_a[t] = ((const float4*)addv)[t];
    }
    // Reverse mapping: block 0 handles the highest rows (most recently touched
    // by k_simexp -> most likely still L3-resident), chasing cache recency.
    int rowBase = (NBLK_U - 1 - blockIdx.x) * 32;
    if (t < 32) s_w[t] = p[rowBase + t] * winv;
    __syncthreads();
    int sub = t >> 7;
    int c4  = t & 127;
    float4 e4 = s_e[c4];
    float4 a4 = s_a[c4];
#pragma unroll 4
    for (int it = 0; it < 16; ++it) {
        int row = rowBase + it * 2 + sub;
        float wr = s_w[it * 2 + sub];
        float4 m4 = ((const float4*)(mem + (size_t)row * M_DIM))[c4];
        f32x4 n4;
        n4.x = m4.x * (1.f - wr * e4.x) + wr * a4.x;
        n4.y = m4.y * (1.f - wr * e4.y) + wr * a4.y;
        n4.z = m4.z * (1.f - wr * e4.z) + wr * a4.z;
        n4.w = m4.w * (1.f - wr * e4.w) + wr * a4.w;
        __builtin_nontemporal_store(n4, (f32x4*)(mem_out + (size_t)row * M_DIM) + c4);
    }
}

extern "C" void kernel_launch(void* const* d_in, const int* in_sizes, int n_in,
                              void* d_out, int out_size, void* d_ws, size_t ws_size,
                              hipStream_t stream) {
    const float* x        = (const float*)d_in[0];
    const float* h0       = (const float*)d_in[1];
    const float* c0       = (const float*)d_in[2];
    const float* memory   = (const float*)d_in[3];
    const float* read_vec = (const float*)d_in[4];
    const float* W_ih     = (const float*)d_in[5];
    const float* b_ih     = (const float*)d_in[6];
    const float* W_hh     = (const float*)d_in[7];
    const float* b_hh     = (const float*)d_in[8];
    const float* W_fc     = (const float*)d_in[9];
    const float* b_fc     = (const float*)d_in[10];
    const float* W_key    = (const float*)d_in[11];
    const float* b_key    = (const float*)d_in[12];
    const float* W_beta   = (const float*)d_in[13];
    const float* b_beta   = (const float*)d_in[14];
    const float* W_erase  = (const float*)d_in[15];
    const float* b_erase  = (const float*)d_in[16];
    const float* W_add    = (const float*)d_in[17];
    const float* b_add    = (const float*)d_in[18];

    float* out      = (float*)d_out;                       // 512
    float* h_out    = out + 512;                           // 1024
    float* c_out    = h_out + 1024;                        // 1024
    float* mem_out  = c_out + 1024;                        // N*M
    float* read_out = mem_out + (size_t)N_ROWS * M_DIM;    // 512

    float* ws     = (float*)d_ws;
    float* kvec   = ws + WS_KVEC;
    float* erase  = ws + WS_ERASE;
    float* addv   = ws + WS_ADD;
    float* scal   = ws + WS_SCAL;
    u32*   ctr    = (u32*)(ws + WS_CTR);
    float* p      = ws + WS_P;
    float* psum   = ws + WS_PSUM;
    float* p2sum  = ws + WS_P2SUM;
    float* part1  = ws + WS_PART1;
    float* part2  = ws + WS_PART2;
    float* o1a    = ws + WS_O1A;
    float* o1b    = ws + WS_O1B;

    k_gatecell<<<1024, 256, 0, stream>>>(x, read_vec, h0, c0, W_ih, b_ih, W_hh, b_hh,
                                         h_out, c_out, ctr);
    k_heads<<<513, 256, 0, stream>>>(h_out, W_fc, b_fc, W_key, b_key, W_beta, b_beta,
                                     W_erase, b_erase, W_add, b_add,
                                     out, kvec, scal, erase, addv);
    k_simexp<<<NBLK_S, 256, 0, stream>>>(memory, kvec, scal, p, psum, p2sum, part1, part2);
    k_update<<<NBLK_U + 64, 256, 0, stream>>>(memory, p, psum, p2sum, part1, part2,
                                              erase, addv, mem_out, read_out,
                                              o1a, o1b, ctr);
}

// Round 18
// 88.513 us; speedup vs baseline: 1.0947x; 1.0947x over previous
//
#include <hip/hip_runtime.h>
#include <math.h>

#define N_ROWS 65536
#define M_DIM  512
#define H_DIM  1024
#define EPS    1e-8f
#define NBLK_S 1024   // k_simexp blocks (64 rows each, 16 per wave)
#define NBLK_U 2048   // k_update stream blocks (32 rows each); +64 merge blocks

typedef float f32x4 __attribute__((ext_vector_type(4)));

__device__ __forceinline__ float sigmoidf_(float v) { return 1.f / (1.f + expf(-v)); }

// ---- workspace layout (floats) ----
#define WS_KVEC  0          // 512
#define WS_ERASE 512        // 512
#define WS_ADD   1024       // 512
#define WS_SCAL  1536       // [0]=beta_raw
#define WS_P     2048       // 65536 unnormalized exp(beta*sim)
#define WS_PSUM  67584      // 1024 per-simexp-block Σp
#define WS_P2SUM 68608      // 1024 per-simexp-block Σp²
#define WS_PART1 69632      // 1024*512 per-block Σ p·mem
#define WS_PART2 593920     // 1024*512 per-block Σ p²·mem
#define WS_O1A   1118208    // 64*512
#define WS_O1B   1150976    // 64*512

// ---- fused gates matvec + LSTM cell: 1024 blocks x 256 ----
__global__ void __launch_bounds__(256) k_gatecell(
        const float* __restrict__ x, const float* __restrict__ rv,
        const float* __restrict__ h0, const float* __restrict__ c0,
        const float* __restrict__ W_ih, const float* __restrict__ b_ih,
        const float* __restrict__ W_hh, const float* __restrict__ b_hh,
        float* __restrict__ h_out, float* __restrict__ c_out) {
    __shared__ float gval[4];
    int j = blockIdx.x;
    int wid = threadIdx.x >> 6;
    int lane = threadIdx.x & 63;
    int r = wid * H_DIM + j;
    const float4* Wi = (const float4*)(W_ih + (size_t)r * 1024);
    const float4* Wh = (const float4*)(W_hh + (size_t)r * 1024);
    const float4* xv = (const float4*)x;
    const float4* rvv = (const float4*)rv;
    const float4* hv = (const float4*)h0;
    float s = 0.f;
#pragma unroll
    for (int k = 0; k < 4; ++k) {
        int idx = k * 64 + lane;
        float4 wiv = Wi[idx];
        float4 in4 = (k < 2) ? xv[idx] : rvv[idx - 128];
        s += wiv.x * in4.x + wiv.y * in4.y + wiv.z * in4.z + wiv.w * in4.w;
        float4 whv = Wh[idx];
        float4 h4 = hv[idx];
        s += whv.x * h4.x + whv.y * h4.y + whv.z * h4.z + whv.w * h4.w;
    }
#pragma unroll
    for (int o = 32; o > 0; o >>= 1) s += __shfl_xor(s, o);
    if (lane == 0) gval[wid] = s + b_ih[r] + b_hh[r];
    __syncthreads();
    if (threadIdx.x == 0) {
        float ig = sigmoidf_(gval[0]);
        float fg = sigmoidf_(gval[1]);
        float gg = tanhf(gval[2]);
        float og = sigmoidf_(gval[3]);
        float c = fg * c0[j] + ig * gg;
        float h = og * tanhf(c);
        c_out[j] = c;
        h_out[j] = h;
    }
}

// ---- 5 head matvecs vs h; one wave per output row ----
__global__ void __launch_bounds__(256) k_heads(
        const float* __restrict__ h,
        const float* __restrict__ W_fc, const float* __restrict__ b_fc,
        const float* __restrict__ W_key, const float* __restrict__ b_key,
        const float* __restrict__ W_beta, const float* __restrict__ b_beta,
        const float* __restrict__ W_erase, const float* __restrict__ b_erase,
        const float* __restrict__ W_add, const float* __restrict__ b_add,
        float* __restrict__ out, float* __restrict__ kvec,
        float* __restrict__ scal, float* __restrict__ erase,
        float* __restrict__ addv) {
    int wave = (blockIdx.x * blockDim.x + threadIdx.x) >> 6;
    int lane = threadIdx.x & 63;
    if (wave >= 2049) return;
    const float* Wrow;
    float bias;
    int kind, r;
    if (wave < 512)        { kind = 0; r = wave;        Wrow = W_fc    + (size_t)r * 1024; bias = b_fc[r]; }
    else if (wave < 1024)  { kind = 1; r = wave - 512;  Wrow = W_key   + (size_t)r * 1024; bias = b_key[r]; }
    else if (wave == 1024) { kind = 2; r = 0;           Wrow = W_beta;                     bias = b_beta[0]; }
    else if (wave < 1537)  { kind = 3; r = wave - 1025; Wrow = W_erase + (size_t)r * 1024; bias = b_erase[r]; }
    else                   { kind = 4; r = wave - 1537; Wrow = W_add   + (size_t)r * 1024; bias = b_add[r]; }
    const float4* Wv = (const float4*)Wrow;
    const float4* hv = (const float4*)h;
    float s = 0.f;
#pragma unroll
    for (int k = 0; k < 4; ++k) {
        int idx = k * 64 + lane;
        float4 w4 = Wv[idx];
        float4 h4 = hv[idx];
        s += w4.x * h4.x + w4.y * h4.y + w4.z * h4.z + w4.w * h4.w;
    }
#pragma unroll
    for (int o = 32; o > 0; o >>= 1) s += __shfl_xor(s, o);
    if (lane == 0) {
        float v = s + bias;
        if (kind == 0)      out[r]   = sigmoidf_(v);
        else if (kind == 1) kvec[r]  = tanhf(v);
        else if (kind == 2) scal[0]  = v;
        else if (kind == 3) erase[r] = sigmoidf_(v);
        else                addv[r]  = tanhf(v);
    }
}

// ---- pass A: p[n]=exp(beta*cos); accumulate per-block R1=Σp·mem, R2=Σp²·mem ----
__global__ void __launch_bounds__(256) k_simexp(
        const float* __restrict__ mem, const float* __restrict__ kvec,
        const float* __restrict__ scal,
        float* __restrict__ p, float* __restrict__ psum, float* __restrict__ p2sum,
        float* __restrict__ part1, float* __restrict__ part2) {
    __shared__ float red[256];
    __shared__ float skn[512];
    __shared__ float wsum[4];
    __shared__ float w2sum[4];
    __shared__ float4 s1[4][128];
    __shared__ float4 s2[4][128];
    int t = threadIdx.x;
    float v0 = kvec[t];
    float v1 = kvec[t + 256];
    red[t] = v0 * v0 + v1 * v1;
    __syncthreads();
#pragma unroll
    for (int s2_ = 128; s2_ > 0; s2_ >>= 1) {
        if (t < s2_) red[t] += red[t + s2_];
        __syncthreads();
    }
    float invn = 1.f / (sqrtf(red[0]) + EPS);
    float braw = scal[0];
    float beta = ((braw > 20.f) ? braw : log1pf(expf(braw))) + EPS;
    skn[t] = v0 * invn;
    skn[t + 256] = v1 * invn;
    __syncthreads();
    int wid = t >> 6, lane = t & 63;
    float4 k0 = ((const float4*)skn)[lane];
    float4 k1 = ((const float4*)skn)[64 + lane];
    size_t base = ((size_t)blockIdx.x * 4 + wid) * 16;   // 16 rows per wave
    float lsum = 0.f, l2sum = 0.f;
    float4 a1lo = make_float4(0.f,0.f,0.f,0.f), a1hi = make_float4(0.f,0.f,0.f,0.f);
    float4 a2lo = make_float4(0.f,0.f,0.f,0.f), a2hi = make_float4(0.f,0.f,0.f,0.f);
#pragma unroll 2
    for (int i = 0; i < 16; ++i) {
        size_t row = base + i;
        const float4* mv = (const float4*)(mem + row * M_DIM);
        float4 m0 = mv[lane];
        float4 m1 = mv[64 + lane];
        float dot = m0.x * k0.x + m0.y * k0.y + m0.z * k0.z + m0.w * k0.w
                  + m1.x * k1.x + m1.y * k1.y + m1.z * k1.z + m1.w * k1.w;
        float ss  = m0.x * m0.x + m0.y * m0.y + m0.z * m0.z + m0.w * m0.w
                  + m1.x * m1.x + m1.y * m1.y + m1.z * m1.z + m1.w * m1.w;
#pragma unroll
        for (int o = 32; o > 0; o >>= 1) {
            dot += __shfl_xor(dot, o);
            ss  += __shfl_xor(ss, o);
        }
        float pe = expf(beta * (dot / (sqrtf(ss) + EPS)));
        if (lane == 0) p[row] = pe;
        float pe2 = pe * pe;
        lsum += pe;
        l2sum += pe2;
        a1lo.x += pe * m0.x;  a1lo.y += pe * m0.y;  a1lo.z += pe * m0.z;  a1lo.w += pe * m0.w;
        a1hi.x += pe * m1.x;  a1hi.y += pe * m1.y;  a1hi.z += pe * m1.z;  a1hi.w += pe * m1.w;
        a2lo.x += pe2 * m0.x; a2lo.y += pe2 * m0.y; a2lo.z += pe2 * m0.z; a2lo.w += pe2 * m0.w;
        a2hi.x += pe2 * m1.x; a2hi.y += pe2 * m1.y; a2hi.z += pe2 * m1.z; a2hi.w += pe2 * m1.w;
    }
    s1[wid][lane] = a1lo;  s1[wid][64 + lane] = a1hi;
    s2[wid][lane] = a2lo;  s2[wid][64 + lane] = a2hi;
    if (lane == 0) { wsum[wid] = lsum; w2sum[wid] = l2sum; }
    __syncthreads();
    if (t < 128) {
        float4 A = s1[0][t], B = s1[1][t], C = s1[2][t], D = s1[3][t];
        float4 r4;
        r4.x = (A.x + B.x) + (C.x + D.x);
        r4.y = (A.y + B.y) + (C.y + D.y);
        r4.z = (A.z + B.z) + (C.z + D.z);
        r4.w = (A.w + B.w) + (C.w + D.w);
        ((float4*)(part1 + (size_t)blockIdx.x * M_DIM))[t] = r4;
    } else {
        int u = t - 128;
        float4 A = s2[0][u], B = s2[1][u], C = s2[2][u], D = s2[3][u];
        float4 r4;
        r4.x = (A.x + B.x) + (C.x + D.x);
        r4.y = (A.y + B.y) + (C.y + D.y);
        r4.z = (A.z + B.z) + (C.z + D.z);
        r4.w = (A.w + B.w) + (C.w + D.w);
        ((float4*)(part2 + (size_t)blockIdx.x * M_DIM))[u] = r4;
    }
    if (t == 0) {
        psum[blockIdx.x]  = (wsum[0] + wsum[1]) + (wsum[2] + wsum[3]);
        p2sum[blockIdx.x] = (w2sum[0] + w2sum[1]) + (w2sum[2] + w2sum[3]);
    }
}

// ---- pass B: 2112 blocks. 0..2047 stream mem_new (REVERSE row order for L3 recency);
//      2048..2111 do merge stage 1 ----
__global__ void __launch_bounds__(256) k_update(
        const float* __restrict__ mem, const float* __restrict__ p,
        const float* __restrict__ psum,
        const float* __restrict__ part1, const float* __restrict__ part2,
        const float* __restrict__ erase, const float* __restrict__ addv,
        float* __restrict__ mem_out,
        float* __restrict__ o1a, float* __restrict__ o1b) {
    int t = threadIdx.x;

    if (blockIdx.x >= NBLK_U) {
        // ---- merge stage 1: 64 blocks; block g sums partials g*16..g*16+15 ----
        int g = blockIdx.x - NBLK_U;
        float s0 = 0.f, s1 = 0.f, s2 = 0.f, s3 = 0.f;
        int b0 = g * 16;
#pragma unroll 4
        for (int b = b0; b < b0 + 16; ++b) {
            s0 += part1[(size_t)b * M_DIM + t];
            s1 += part1[(size_t)b * M_DIM + 256 + t];
            s2 += part2[(size_t)b * M_DIM + t];
            s3 += part2[(size_t)b * M_DIM + 256 + t];
        }
        o1a[(size_t)g * M_DIM + t] = s0;
        o1a[(size_t)g * M_DIM + 256 + t] = s1;
        o1b[(size_t)g * M_DIM + t] = s2;
        o1b[(size_t)g * M_DIM + 256 + t] = s3;
        return;
    }

    // ---- stream blocks ----
    __shared__ float red[256];
    __shared__ float4 s_e[128];
    __shared__ float4 s_a[128];
    __shared__ float  s_w[32];
    float s = 0.f;
#pragma unroll
    for (int i = 0; i < 4; ++i) s += psum[t + i * 256];
    red[t] = s;
    __syncthreads();
#pragma unroll
    for (int s2_ = 128; s2_ > 0; s2_ >>= 1) {
        if (t < s2_) red[t] += red[t + s2_];
        __syncthreads();
    }
    float winv = 1.f / red[0];
    if (t < 128) {
        s_e[t] = ((const float4*)erase)[t];
        s_a[t] = ((const float4*)addv)[t];
    }
    // REVERSE mapping: block 0 handles the highest rows (most recently touched
    // by k_simexp -> most likely still L3-resident), chasing cache recency.
    int rowBase = (NBLK_U - 1 - blockIdx.x) * 32;
    if (t < 32) s_w[t] = p[rowBase + t] * winv;
    __syncthreads();
    int sub = t >> 7;
    int c4  = t & 127;
    float4 e4 = s_e[c4];
    float4 a4 = s_a[c4];
#pragma unroll 4
    for (int it = 0; it < 16; ++it) {
        int row = rowBase + it * 2 + sub;
        float wr = s_w[it * 2 + sub];
        float4 m4 = ((const float4*)(mem + (size_t)row * M_DIM))[c4];
        f32x4 n4;
        n4.x = m4.x * (1.f - wr * e4.x) + wr * a4.x;
        n4.y = m4.y * (1.f - wr * e4.y) + wr * a4.y;
        n4.z = m4.z * (1.f - wr * e4.z) + wr * a4.z;
        n4.w = m4.w * (1.f - wr * e4.w) + wr * a4.w;
        __builtin_nontemporal_store(n4, (f32x4*)(mem_out + (size_t)row * M_DIM) + c4);
    }
}

// ---- merge stage 2: 1 block x 512; read_new = R1/S - e*R2/S² + a*P2/S² ----
__global__ void __launch_bounds__(512) k_merge2(
        const float* __restrict__ o1a, const float* __restrict__ o1b,
        const float* __restrict__ psum, const float* __restrict__ p2sum,
        const float* __restrict__ erase, const float* __restrict__ addv,
        float* __restrict__ read_new) {
    __shared__ float red[512];
    __shared__ float red2[512];
    int t = threadIdx.x;
    red[t]  = psum[t] + psum[t + 512];
    red2[t] = p2sum[t] + p2sum[t + 512];
    __syncthreads();
#pragma unroll
    for (int s2_ = 256; s2_ > 0; s2_ >>= 1) {
        if (t < s2_) { red[t] += red[t + s2_]; red2[t] += red2[t + s2_]; }
        __syncthreads();
    }
    float invS  = 1.f / red[0];
    float sumP2 = red2[0];
    float invSS = invS * invS;
    float r1 = 0.f, r2 = 0.f;
#pragma unroll 4
    for (int g = 0; g < 64; ++g) {
        r1 += o1a[(size_t)g * M_DIM + t];
        r2 += o1b[(size_t)g * M_DIM + t];
    }
    read_new[t] = r1 * invS - erase[t] * r2 * invSS + addv[t] * sumP2 * invSS;
}

extern "C" void kernel_launch(void* const* d_in, const int* in_sizes, int n_in,
                              void* d_out, int out_size, void* d_ws, size_t ws_size,
                              hipStream_t stream) {
    const float* x        = (const float*)d_in[0];
    const float* h0       = (const float*)d_in[1];
    const float* c0       = (const float*)d_in[2];
    const float* memory   = (const float*)d_in[3];
    const float* read_vec = (const float*)d_in[4];
    const float* W_ih     = (const float*)d_in[5];
    const float* b_ih     = (const float*)d_in[6];
    const float* W_hh     = (const float*)d_in[7];
    const float* b_hh     = (const float*)d_in[8];
    const float* W_fc     = (const float*)d_in[9];
    const float* b_fc     = (const float*)d_in[10];
    const float* W_key    = (const float*)d_in[11];
    const float* b_key    = (const float*)d_in[12];
    const float* W_beta   = (const float*)d_in[13];
    const float* b_beta   = (const float*)d_in[14];
    const float* W_erase  = (const float*)d_in[15];
    const float* b_erase  = (const float*)d_in[16];
    const float* W_add    = (const float*)d_in[17];
    const float* b_add    = (const float*)d_in[18];

    float* out      = (float*)d_out;                       // 512
    float* h_out    = out + 512;                           // 1024
    float* c_out    = h_out + 1024;                        // 1024
    float* mem_out  = c_out + 1024;                        // N*M
    float* read_out = mem_out + (size_t)N_ROWS * M_DIM;    // 512

    float* ws     = (float*)d_ws;
    float* kvec   = ws + WS_KVEC;
    float* erase  = ws + WS_ERASE;
    float* addv   = ws + WS_ADD;
    float* scal   = ws + WS_SCAL;
    float* p      = ws + WS_P;
    float* psum   = ws + WS_PSUM;
    float* p2sum  = ws + WS_P2SUM;
    float* part1  = ws + WS_PART1;
    float* part2  = ws + WS_PART2;
    float* o1a    = ws + WS_O1A;
    float* o1b    = ws + WS_O1B;

    k_gatecell<<<1024, 256, 0, stream>>>(x, read_vec, h0, c0, W_ih, b_ih, W_hh, b_hh,
                                         h_out, c_out);
    k_heads<<<513, 256, 0, stream>>>(h_out, W_fc, b_fc, W_key, b_key, W_beta, b_beta,
                                     W_erase, b_erase, W_add, b_add,
                                     out, kvec, scal, erase, addv);
    k_simexp<<<NBLK_S, 256, 0, stream>>>(memory, kvec, scal, p, psum, p2sum, part1, part2);
    k_update<<<NBLK_U + 64, 256, 0, stream>>>(memory, p, psum, part1, part2,
                                              erase, addv, mem_out, o1a, o1b);
    k_merge2<<<1, 512, 0, stream>>>(o1a, o1b, psum, p2sum, erase, addv, read_out);
}